// Round 6
// baseline (189.595 us; speedup 1.0000x reference)
//
#include <hip/hip_runtime.h>

typedef __bf16 bf16;
typedef __bf16 bf16x8 __attribute__((ext_vector_type(8)));
typedef float f32x4 __attribute__((ext_vector_type(4)));
typedef unsigned int u32;

#define NB    2048
#define NM    26
#define NROWS 65536   // (b,k) pairs
#define NJP   28      // 26 j-chunks + 2 zero pad (unconditional prefetch)

// ---------------- prep kernels ----------------

// xb[(b*32+k)*32 + j] = inputs[b][j][k]  (j>=26 -> 0)
__global__ __launch_bounds__(256) void prep_x(const float* __restrict__ in, bf16* __restrict__ xb) {
  int e = blockIdx.x * 256 + threadIdx.x;
  int row = e >> 5, j = e & 31;
  int b = row >> 5, k = row & 31;
  float v = (j < NM) ? in[b*(NM*32) + j*32 + k] : 0.f;
  xb[e] = (bf16)v;
}

// xbT[j][row] = pair-duplicated bf16 of inputs[b][j][k]  (row=(b,k)); j>=26 -> 0
__global__ __launch_bounds__(256) void prep_xT(const float* __restrict__ in, u32* __restrict__ xbT) {
  int e = blockIdx.x * 256 + threadIdx.x;      // [0, NJP*NROWS)
  int j = e >> 16, row = e & 65535;
  float v = (j < NM) ? in[(row >> 5)*(NM*32) + j*32 + (row & 31)] : 0.f;
  union { bf16 h; unsigned short s; } cv; cv.h = (bf16)v;
  xbT[e] = (u32)cv.s * 0x10001u;
}

// w1t: tiles [cs_idx(2)][c(NJP)] of [r(64)][i(32)] = W1[h=cs_idx*64+r][i][c]; pad/i>=26 -> 0
__global__ __launch_bounds__(256) void prep_w1t(const float* __restrict__ w, bf16* __restrict__ wt) {
  int e = blockIdx.x * 256 + threadIdx.x;      // [0, 2*NJP*2048)
  int i = e & 31, r = (e >> 5) & 63;
  int rest = e >> 11;
  int c = rest % NJP, cs_idx = rest / NJP;
  int h = cs_idx*64 + r;
  float v = (i < NM && c < NM) ? w[h*(NM*NM) + i*NM + c] : 0.f;
  wt[e] = (bf16)v;
}

// w2t: tiles [cs_idx(2)][ii(4)][j(NJP)] of [r(64)][c(32)] = W2[h=cs_idx*64+r][i=ii*32+c][j]; pad -> 0
__global__ __launch_bounds__(256) void prep_w2t(const float* __restrict__ w, bf16* __restrict__ wt) {
  int e = blockIdx.x * 256 + threadIdx.x;      // [0, 8*NJP*2048)
  int c = e & 31, r = (e >> 5) & 63;
  int rest = e >> 11;
  int j = rest % NJP, q = rest / NJP;          // q = cs_idx*4 + ii
  int ii = q & 3, cs_idx = q >> 2;
  int h = cs_idx*64 + r, i = ii*32 + c;
  float v = (j < NM) ? w[h*(128*NM) + i*NM + j] : 0.f;
  wt[e] = (bf16)v;
}

__device__ __forceinline__ bf16x8 splat8(u32 p) {
  union { u32 u[4]; bf16x8 v; } s;
  s.u[0] = p; s.u[1] = p; s.u[2] = p; s.u[3] = p;
  return s.v;
}

// one K-chunk step: prefetch chunk JN into buf NXT, compute with buf CUR
#define CIN_STEP(CUR, NXT, JN, TSTRIDE) do {                                   \
  _Pragma("unroll")                                                            \
  for (int ni = 0; ni < 4; ++ni)                                               \
    B[NXT][ni] = *(const bf16x8*)(tb + (long)(JN)*2048 + ni*512);              \
  _Pragma("unroll")                                                            \
  for (int mi = 0; mi < 4; ++mi)                                               \
    sc[NXT][mi] = sp[(JN)*NROWS + mi*16];                                      \
  _Pragma("unroll")                                                            \
  for (int mi = 0; mi < 4; ++mi) {                                             \
    bf16x8 af = xf[mi] * splat8(sc[CUR][mi]);                                  \
    _Pragma("unroll")                                                          \
    for (int ni = 0; ni < 4; ++ni)                                             \
      acc[mi][ni] = __builtin_amdgcn_mfma_f32_16x16x32_bf16(af, B[CUR][ni],    \
                                                            acc[mi][ni], 0, 0, 0); \
  }                                                                            \
} while (0)

// ---------------- layer 1: 2048 waves, wave = 64 rows x 64 cols, K=832 --------
__global__ __launch_bounds__(256, 4) void cin1(
    const bf16* __restrict__ xb, const u32* __restrict__ xbT,
    const bf16* __restrict__ w1t, const float* __restrict__ b1,
    bf16* __restrict__ x1b, float* __restrict__ out)
{
  const int t = threadIdx.x;
  const int lane = t & 63, w = t >> 6;
  const int strip = blockIdx.x*2 + (w >> 1);
  const int cs_idx = w & 1, cs = cs_idx * 64;
  const int rowBase = strip * 64;
  const int lr = lane & 15, lq = lane >> 4;

  bf16x8 xf[4];
  #pragma unroll
  for (int mi = 0; mi < 4; ++mi)
    xf[mi] = *(const bf16x8*)&xb[(rowBase + mi*16 + lr)*32 + lq*8];

  f32x4 acc[4][4];
  #pragma unroll
  for (int mi=0; mi<4; ++mi)
    #pragma unroll
    for (int ni=0; ni<4; ++ni) acc[mi][ni] = {0.f,0.f,0.f,0.f};

  const bf16* tb = w1t + (long)cs_idx*NJP*2048 + (lr*32 + lq*8);
  const u32*  sp = xbT + rowBase + lr;

  bf16x8 B[2][4];
  u32 sc[2][4];
  #pragma unroll
  for (int ni=0; ni<4; ++ni) B[0][ni] = *(const bf16x8*)(tb + ni*512);
  #pragma unroll
  for (int mi=0; mi<4; ++mi) sc[0][mi] = sp[mi*16];

  for (int jj = 0; jj < 13; ++jj) {
    const int j = 2*jj;
    CIN_STEP(0, 1, j+1, 832);
    CIN_STEP(1, 0, j+2, 832);
  }

  float bias[4];
  #pragma unroll
  for (int ni=0; ni<4; ++ni) bias[ni] = b1[cs + ni*16 + lr];
  #pragma unroll
  for (int mi=0; mi<4; ++mi)
    #pragma unroll
    for (int ni=0; ni<4; ++ni) {
      int col = cs + ni*16 + lr;
      #pragma unroll
      for (int r=0; r<4; ++r) {
        int row = rowBase + mi*16 + lq*4 + r;
        x1b[row*128 + col] = (bf16)(acc[mi][ni][r] + bias[ni]);
      }
    }
  #pragma unroll
  for (int half=0; half<2; ++half) {
    int b = (rowBase >> 5) + half;
    #pragma unroll
    for (int ni=0; ni<4; ++ni) {
      float v = 0.f;
      #pragma unroll
      for (int mi=0; mi<2; ++mi)
        #pragma unroll
        for (int r=0; r<4; ++r) v += acc[half*2+mi][ni][r];
      v += __shfl_xor(v, 16, 64);
      v += __shfl_xor(v, 32, 64);
      if (lq == 0) out[b*256 + cs + ni*16 + lr] = v + 32.0f * bias[ni];
    }
  }
}

// ---------------- layer 2: 8192 waves, split-K x4, K=3328 ---------------------
__global__ __launch_bounds__(256, 4) void cin2(
    const u32* __restrict__ xbT, const bf16* __restrict__ x1b,
    const bf16* __restrict__ w2t, float* __restrict__ p2)
{
  const int t = threadIdx.x;
  const int lane = t & 63, w = t >> 6;
  const int strip = blockIdx.x >> 1;
  const int cs_idx = blockIdx.x & 1, cs = cs_idx * 64;
  const int ii = w;
  const int rowBase = strip * 64;
  const int lr = lane & 15, lq = lane >> 4;

  bf16x8 xf[4];
  #pragma unroll
  for (int mi = 0; mi < 4; ++mi)
    xf[mi] = *(const bf16x8*)&x1b[(rowBase + mi*16 + lr)*128 + ii*32 + lq*8];

  f32x4 acc[4][4];
  #pragma unroll
  for (int mi=0; mi<4; ++mi)
    #pragma unroll
    for (int ni=0; ni<4; ++ni) acc[mi][ni] = {0.f,0.f,0.f,0.f};

  const bf16* tb = w2t + ((long)(cs_idx*4 + ii))*NJP*2048 + (lr*32 + lq*8);
  const u32*  sp = xbT + rowBase + lr;

  bf16x8 B[2][4];
  u32 sc[2][4];
  #pragma unroll
  for (int ni=0; ni<4; ++ni) B[0][ni] = *(const bf16x8*)(tb + ni*512);
  #pragma unroll
  for (int mi=0; mi<4; ++mi) sc[0][mi] = sp[mi*16];

  for (int jj = 0; jj < 13; ++jj) {
    const int j = 2*jj;
    CIN_STEP(0, 1, j+1, 3328);
    CIN_STEP(1, 0, j+2, 3328);
  }

  // partial k-sums to p2[ii][b][col]; 64 rows = 2 b's
  #pragma unroll
  for (int half=0; half<2; ++half) {
    int b = (rowBase >> 5) + half;
    #pragma unroll
    for (int ni=0; ni<4; ++ni) {
      float v = 0.f;
      #pragma unroll
      for (int mi=0; mi<2; ++mi)
        #pragma unroll
        for (int r=0; r<4; ++r) v += acc[half*2+mi][ni][r];
      v += __shfl_xor(v, 16, 64);
      v += __shfl_xor(v, 32, 64);
      if (lq == 0) p2[(ii*NB + b)*128 + cs + ni*16 + lr] = v;
    }
  }
}

// ---------------- combine: out[b][128+col] = sum_ii p2 + 32*b2 ----------------
__global__ __launch_bounds__(256) void combine(
    const float* __restrict__ p2, const float* __restrict__ b2, float* __restrict__ out)
{
  int idx = blockIdx.x * 256 + threadIdx.x;   // [0, NB*128)
  int b = idx >> 7, col = idx & 127;
  float v = 32.0f * b2[col];
  #pragma unroll
  for (int ii=0; ii<4; ++ii) v += p2[(ii*NB + b)*128 + col];
  out[b*256 + 128 + col] = v;
}

// ---------------- launch ----------------
extern "C" void kernel_launch(void* const* d_in, const int* in_sizes, int n_in,
                              void* d_out, int out_size, void* d_ws, size_t ws_size,
                              hipStream_t stream) {
  const float* in = (const float*)d_in[0];
  const float* W1 = (const float*)d_in[1];
  const float* b1 = (const float*)d_in[2];
  const float* W2 = (const float*)d_in[3];
  const float* b2 = (const float*)d_in[4];
  float* out = (float*)d_out;

  char* ws = (char*)d_ws;
  bf16* xb  = (bf16*)(ws);                 // 65536*32*2      = 4,194,304
  u32*  xbT = (u32*) (ws + 4194304);       // 28*65536*4      = 7,340,032
  bf16* w1t = (bf16*)(ws + 11534336);      // 2*28*2048*2     = 229,376
  bf16* w2t = (bf16*)(ws + 11763712);      // 8*28*2048*2     = 917,504
  bf16* x1b = (bf16*)(ws + 12681216);      // 65536*128*2     = 16,777,216
  float* p2 = (float*)(ws + 29458432);     // 4*2048*128*4    = 4,194,304  (end ~33.7 MB)

  prep_x  <<<NROWS*32/256,     256, 0, stream>>>(in, xb);
  prep_xT <<<NJP*NROWS/256,    256, 0, stream>>>(in, xbT);
  prep_w1t<<<2*NJP*2048/256,   256, 0, stream>>>(W1, w1t);
  prep_w2t<<<8*NJP*2048/256,   256, 0, stream>>>(W2, w2t);
  cin1    <<<512,              256, 0, stream>>>(xb, xbT, w1t, b1, x1b, out);
  cin2    <<<2048,             256, 0, stream>>>(xbT, x1b, w2t, p2);
  combine <<<NB*128/256,       256, 0, stream>>>(p2, b2, out);
}